// Round 1
// 66.804 us; speedup vs baseline: 1.0048x; 1.0048x over previous
//
#include <hip/hip_runtime.h>

// Sinkhorn loss, fully fused, MFMA edition v6 — single dispatch.
// One block per batch (b=16), n=48x48=2304, 5 iterations.
//
// v6 changes vs v5:
//  - Analytic half-0: with W == 1, S0[(c,r)] = s[c]*s[r] where s = row sums
//    of the 48x48 Toeplitz factor T. Row sums are accumulated in f32 during
//    the fragment prologue (free), quad-reduced via shfl_xor, staged through
//    48 floats of LDS under the existing init barrier. Removes one full
//    matmul stage-pair (2 LDS round trips + 8 MFMAs + 1 barrier) and the
//    all-ones body init of sW (pads still zeroed).
//  - Cross-block finish packs {FLAG_MAGIC, payload} into ONE 64-bit release
//    store per block; block 0 polls a single 64-bit acquire load per peer.
//    Workspace 0xAA-poison (0xAAAAAAAA........) can never alias the magic
//    upper word. One release-flush per block instead of store+release-store.
//  - 100*EPS == 1  =>  w' = w * mu / (w*S + 1e-6): no log/exp in the loop.

#define TPB 576      // 9 waves = 9 MFMA tiles of 16x16 = 48x48
#define STRIDE 72    // shorts per LDS matrix row (144 B, 16B-aligned frags)
#define FLAG_MAGIC 0x5CA1AB1Eu

typedef __attribute__((ext_vector_type(8))) short short8;
typedef __attribute__((ext_vector_type(4))) short short4v;
typedef __attribute__((ext_vector_type(4))) float f32x4;

__device__ __forceinline__ void splitb(float x, short& hi, short& lo) {
    union { float f; unsigned u; } a, h;
    a.f = x;
    h.u = a.u & 0xffff0000u;          // truncate; lo captures residual
    hi  = (short)(h.u >> 16);
    union { float f; unsigned u; } l;
    l.f = x - h.f;
    lo  = (short)(l.u >> 16);
}

__device__ __forceinline__ short bf16rne(float x) {
    union { float f; unsigned u; } a;
    a.f = x;
    unsigned r = a.u + 0x7fffu + ((a.u >> 16) & 1u);
    return (short)(r >> 16);
}

__device__ __forceinline__ f32x4 mm16(short8 a, short8 b, f32x4 c) {
    return __builtin_amdgcn_mfma_f32_16x16x32_bf16(a, b, c, 0, 0, 0);
}

__global__ __launch_bounds__(TPB) void sinkhorn_kernel(const float* __restrict__ y,
                                                       const float* __restrict__ yt,
                                                       unsigned long long* __restrict__ slots,
                                                       float* __restrict__ out)
{
    __shared__ __align__(16) short sW [48 * STRIDE];  // current W (row-major)
    __shared__ __align__(16) short sP [48 * STRIDE];  // stage-1 out (transposed)
    __shared__ __align__(16) short sP2[48 * STRIDE];  // final-cost second buf
    __shared__ float red[32];
    __shared__ __align__(16) float sRow[48];          // f32 row sums of T

    const int t    = threadIdx.x;
    const int b    = blockIdx.x;
    const int lane = t & 63;
    const int wid  = t >> 6;            // wave id 0..8
    const int tr   = wid / 3;           // tile row
    const int tc   = wid - tr * 3;      // tile col
    const int n15  = lane & 15;
    const int quad = lane >> 4;
    const int kq   = quad * 8;
    const int r0   = tr * 16 + quad * 4;   // C/D row base
    const int c    = tc * 16 + n15;        // C/D col; also T-register row
    const int aBase  = (tr * 16 + n15) * STRIDE;      // A-frag row base (LDS)
    const int stBase = c * STRIDE + r0;               // transpose-store base
    // lane's elementwise slots: logical (c, r0+rg), rg = 0..3

    // ---- global input loads FIRST (float4; hide cold-miss under exp init) ----
    const f32x4 y4  = *(const f32x4*)(y  + b * 2304 + c * 48 + r0);
    const f32x4 yt4 = *(const f32x4*)(yt + b * 2304 + c * 48 + r0);

    // ---- T / TD register fragments, row c, hi/lo bf16 split (B-slot use) ----
    // Also accumulate the f32 row-sum of T row c (for the analytic half-0).
    short8 Th0, Th1, Tl0, Tl1, Dh0, Dh1, Dl0, Dl1;
    float rs = 0.f;
    {
        const float gm = (float)c / 48.0f;
#pragma unroll
        for (int kk = 0; kk < 8; ++kk) {
            int k0 = kq + kk;
            float d = gm - (float)k0 / 48.0f;
            float dsq = d * d;
            float e = __expf(-100.0f * dsq);
            rs += e;
            short h, l;
            splitb(e, h, l);        Th0[kk] = h; Tl0[kk] = l;
            splitb(e * dsq, h, l);  Dh0[kk] = h; Dl0[kk] = l;
            int k1 = k0 + 32;
            if (k1 < 48) {
                float d1 = gm - (float)k1 / 48.0f;
                float q1 = d1 * d1;
                float e1 = __expf(-100.0f * q1);
                rs += e1;
                splitb(e1, h, l);       Th1[kk] = h; Tl1[kk] = l;
                splitb(e1 * q1, h, l);  Dh1[kk] = h; Dl1[kk] = l;
            } else {
                Th1[kk] = 0; Tl1[kk] = 0; Dh1[kk] = 0; Dl1[kk] = 0;
            }
        }
    }
    // quad-reduce: lanes sharing n15 hold disjoint k-ranges of row c
    rs += __shfl_xor(rs, 16);
    rs += __shfl_xor(rs, 32);          // rs = s[c] in every lane
    if (wid < 3 && quad == 0) sRow[wid * 16 + n15] = rs;  // waves 0-2: c = wid*16+n15

    // ---- init LDS K-pads only (body of sW is written pre-loop; sP/sP2 in stages)
    if (t < 432) {
        int ccol = t % 9;
        if (ccol >= 6) {
            const short8 zer = {0, 0, 0, 0, 0, 0, 0, 0};
            ((short8*)sW )[t] = zer;
            ((short8*)sP )[t] = zer;
            ((short8*)sP2)[t] = zer;
        }
    }

    // ---- masses at slots (c, r0+rg) ----
    float mx[4], my[4];
#pragma unroll
    for (int rg = 0; rg < 4; ++rg) {
        mx[rg] = fminf(fmaxf(y4[rg],  0.f), 1e9f) + 1e-9f;
        my[rg] = fminf(fmaxf(yt4[rg], 0.f), 1e9f) + 1e-9f;
    }
    float sx = mx[0] + mx[1] + mx[2] + mx[3];
    float sy = my[0] + my[1] + my[2] + my[3];
#pragma unroll
    for (int off = 32; off > 0; off >>= 1) {
        sx += __shfl_down(sx, off);
        sy += __shfl_down(sy, off);
    }
    if (lane == 0) { red[wid] = sx; red[16 + wid] = sy; }
    __syncthreads();   // covers LDS pad init + sRow writes
    float ax = 0.f, ay = 0.f;
#pragma unroll
    for (int w = 0; w < TPB / 64; ++w) { ax += red[w]; ay += red[16 + w]; }
    const float rsx = 1.0f / ax, rsy = 1.0f / ay;

    float mu_[4], nu_[4];
#pragma unroll
    for (int q = 0; q < 4; ++q) { mu_[q] = mx[q] * rsx; nu_[q] = my[q] * rsy; }

    // ---- analytic half-0 (u-update with W == 1): S0 = s[c]*s[r] ----
    float wu_[4], wv_[4] = {1, 1, 1, 1};   // exp(u/eps), exp(v/eps)
    {
        const f32x4 sr4 = *(const f32x4*)(sRow + r0);
        short4v wk;
#pragma unroll
        for (int q = 0; q < 4; ++q) {
            wu_[q] = mu_[q] / (rs * sr4[q] + 1e-6f);   // w=1: w' = mu/(S0+1e-6)
            wk[q]  = bf16rne(wu_[q]);
        }
        *(short4v*)(sW + stBase) = wk;
    }
    __syncthreads();

    const f32x4 zz = {0.f, 0.f, 0.f, 0.f};

    // ---- 9 remaining half-iterations: v-update (odd) / u-update (even) ----
    for (int half = 1; half < 10; ++half) {
        // stage 1: D1 = W @ T; store D1^T (b64)
        {
            short8 a0 = *(const short8*)(sW + aBase + kq);
            short8 a1 = *(const short8*)(sW + aBase + kq + 32);
            f32x4 x  = mm16(a0, Th0, zz);
            f32x4 yy = mm16(a1, Th1, zz);
            x  = mm16(a0, Tl0, x);
            yy = mm16(a1, Tl1, yy);
            f32x4 p = x + yy;
            short4v pk;
#pragma unroll
            for (int rg = 0; rg < 4; ++rg) pk[rg] = bf16rne(p[rg]);
            *(short4v*)(sP + stBase) = pk;
        }
        __syncthreads();
        // stage 2: D2 = (D1^T) @ T = S^T at slots; update state; store W' (b64)
        {
            short8 a0 = *(const short8*)(sP + aBase + kq);
            short8 a1 = *(const short8*)(sP + aBase + kq + 32);
            f32x4 x  = mm16(a0, Th0, zz);
            f32x4 yy = mm16(a1, Th1, zz);
            x  = mm16(a0, Tl0, x);
            yy = mm16(a1, Tl1, yy);
            f32x4 S = x + yy;          // S at logical (c, r0+rg)
            float* wc       = ((half & 1) == 0) ? wu_ : wv_;
            const float* m_ = ((half & 1) == 0) ? mu_ : nu_;
            short4v wk;
#pragma unroll
            for (int q = 0; q < 4; ++q) {
                // 100*eps == 1:  w' = e^{u'/eps} = w * mu / (w*S + 1e-6)
                wc[q] = wc[q] * m_[q] / (wc[q] * S[q] + 1e-6f);
                wk[q] = bf16rne(wc[q]);
            }
            *(short4v*)(sW + stBase) = wk;
        }
        __syncthreads();
    }

    // ---- final cost: G = TD@Wv@T + T@Wv@TD, cost = sum wu .* G ----
    {
        short8 a0 = *(const short8*)(sW + aBase + kq);
        short8 a1 = *(const short8*)(sW + aBase + kq + 32);
        f32x4 x1 = mm16(a0, Th0, zz), w1 = mm16(a1, Th1, zz);
        x1 = mm16(a0, Tl0, x1);  w1 = mm16(a1, Tl1, w1);
        f32x4 p1 = x1 + w1;                       // Wv @ T
        f32x4 x2 = mm16(a0, Dh0, zz), w2 = mm16(a1, Dh1, zz);
        x2 = mm16(a0, Dl0, x2);  w2 = mm16(a1, Dl1, w2);
        f32x4 p2 = x2 + w2;                       // Wv @ TD
        short4v k1, k2;
#pragma unroll
        for (int rg = 0; rg < 4; ++rg) { k1[rg] = bf16rne(p1[rg]); k2[rg] = bf16rne(p2[rg]); }
        *(short4v*)(sP  + stBase) = k1;
        *(short4v*)(sP2 + stBase) = k2;
    }
    __syncthreads();
    float local;
    {
        short8 a0 = *(const short8*)(sP  + aBase + kq);
        short8 a1 = *(const short8*)(sP  + aBase + kq + 32);
        short8 c0 = *(const short8*)(sP2 + aBase + kq);
        short8 c1 = *(const short8*)(sP2 + aBase + kq + 32);
        f32x4 x  = mm16(a0, Dh0, zz), yy = mm16(a1, Dh1, zz);
        x  = mm16(a0, Dl0, x);   yy = mm16(a1, Dl1, yy);
        x  = mm16(c0, Th0, x);   yy = mm16(c1, Th1, yy);
        x  = mm16(c0, Tl0, x);   yy = mm16(c1, Tl1, yy);
        f32x4 G = x + yy;          // G at logical (c, r0+rg)
        local = wu_[0] * G[0] + wu_[1] * G[1] + wu_[2] * G[2] + wu_[3] * G[3];
    }
#pragma unroll
    for (int off = 32; off > 0; off >>= 1) local += __shfl_down(local, off);
    if (lane == 0) red[wid] = local;
    __syncthreads();
    float total = 0.f;
#pragma unroll
    for (int w = 0; w < TPB / 64; ++w) total += red[w];

    // ---- cross-block finish: one packed 64-bit release store per block ----
    if (b != 0) {
        if (t == 0) {
            union { float f; unsigned u; } pu; pu.f = total;
            unsigned long long packed =
                ((unsigned long long)FLAG_MAGIC << 32) | (unsigned long long)pu.u;
            __hip_atomic_store(&slots[b], packed, __ATOMIC_RELEASE,
                               __HIP_MEMORY_SCOPE_AGENT);
        }
    } else if (wid == 0) {
        float pv = 0.f;
        if (lane >= 1 && lane < 16) {
            unsigned long long v;
            do {
                v = __hip_atomic_load(&slots[lane], __ATOMIC_ACQUIRE,
                                      __HIP_MEMORY_SCOPE_AGENT);
            } while ((unsigned)(v >> 32) != FLAG_MAGIC);
            union { unsigned u; float f; } pw; pw.u = (unsigned)v; pv = pw.f;
        }
        if (lane == 0) pv = total;
#pragma unroll
        for (int off = 8; off > 0; off >>= 1) pv += __shfl_down(pv, off);
        if (lane == 0) out[0] = pv * (1.0f / 16.0f);
    }
}

extern "C" void kernel_launch(void* const* d_in, const int* in_sizes, int n_in,
                              void* d_out, int out_size, void* d_ws, size_t ws_size,
                              hipStream_t stream)
{
    (void)in_sizes; (void)n_in; (void)ws_size; (void)out_size;
    const float* y  = (const float*)d_in[0];
    const float* yt = (const float*)d_in[1];
    unsigned long long* slots = (unsigned long long*)d_ws;  // ws[0..15] x 8B, 0xAA-poisoned
    float* out = (float*)d_out;

    sinkhorn_kernel<<<16, TPB, 0, stream>>>(y, yt, slots, out);
}